// Round 12
// baseline (82.830 us; speedup 1.0000x reference)
//
#include <hip/hip_runtime.h>
#include <hip/hip_bf16.h>
#include <math.h>

#define NB 128    // batches after reshape
#define NC 768    // channels (rows)
#define NE 64     // inner dim (cols)
#define IPG 12    // channels per conv group

// q pre-scale: 1/8 (SDPA) * log2(e) so attn softmax is exp2(S) on v_exp_f32
#define QSCALE 0.18033688011112042f

typedef __hip_bfloat16 bf16;
typedef __bf16 bf16v8 __attribute__((ext_vector_type(8)));
typedef __bf16 bf16v4 __attribute__((ext_vector_type(4)));
typedef __bf16 bf16v2 __attribute__((ext_vector_type(2)));
typedef float f32x4 __attribute__((ext_vector_type(4)));
typedef float f32x16 __attribute__((ext_vector_type(16)));
typedef unsigned int u32;
typedef u32 u32x4 __attribute__((ext_vector_type(4)));

// gelu = x * Phi(x); Phi via Abramowitz-Stegun 26.2.17 (|err| < 7.5e-8).
__device__ __forceinline__ float gelu_exact(float x) {
    float ax = fabsf(x);
    float t = __builtin_amdgcn_rcpf(fmaf(0.2316419f, ax, 1.0f));
    float poly = t * fmaf(t, fmaf(t, fmaf(t, fmaf(t, 1.330274429f,
                  -1.821255978f), 1.781477937f), -0.356563782f), 0.319381530f);
    float pdf = 0.3989422804f * __expf(-0.5f * ax * ax);
    float c = fmaf(-pdf, poly, 1.0f);
    float cdf = (x >= 0.f) ? c : 1.0f - c;
    return x * cdf;
}

#define MFMA16(a, b, c) __builtin_amdgcn_mfma_f32_16x16x32_bf16(a, b, c, 0, 0, 0)
#define MFMA32(a, b, c) __builtin_amdgcn_mfma_f32_32x32x16_bf16(a, b, c, 0, 0, 0)

__device__ __forceinline__ void gload_lds16(const void* g, void* l) {
    __builtin_amdgcn_global_load_lds(
        (const __attribute__((address_space(1))) void*)g,
        (__attribute__((address_space(3))) void*)l, 16, 0, 0);
}

__device__ __forceinline__ u32 pkbf(float a, float b) {
    bf16v2 t; t[0] = (__bf16)a; t[1] = (__bf16)b;
    return __builtin_bit_cast(u32, t);
}

// ---------------------------------------------------------------------------
// Kernel 1: q path (conv+res+gelu+LN, pre-scaled) + column exp-sum partials.
// ---------------------------------------------------------------------------
__global__ __launch_bounds__(256) void k_conv(
    const float* __restrict__ x, const float* __restrict__ cw,
    const float* __restrict__ cb, const float* __restrict__ lg,
    const float* __restrict__ lb, bf16* __restrict__ qo,
    float* __restrict__ sp)
{
    int b = blockIdx.x >> 4;
    int chunk = blockIdx.x & 15;
    int w = threadIdx.x >> 6;
    int g = __builtin_amdgcn_readfirstlane(chunk * 4 + w);   // wave-uniform
    int h = threadIdx.x & 63;
    const float* xb = x + ((size_t)b * NC + g * IPG) * NE;

    float xi[IPG], xm[IPG], xp[IPG];
    #pragma unroll
    for (int i = 0; i < IPG; ++i) {
        xi[i] = xb[i * NE + h];
        float up = __shfl_up(xi[i], 1);
        float dn = __shfl_down(xi[i], 1);
        xm[i] = h ? up : 0.f;
        xp[i] = (h < 63) ? dn : 0.f;
    }

    // column exp-sum partial over this block's 48 rows
    float es = 0.f;
    #pragma unroll
    for (int i = 0; i < IPG; ++i) es += __expf(xi[i]);
    __shared__ float red[4][64];
    red[w][h] = es;
    __syncthreads();
    if (w == 0) {
        float s = red[0][h] + red[1][h] + red[2][h] + red[3][h];
        sp[(size_t)(b * 16 + chunk) * 64 + h] = s;
    }

    float gam = lg[h], bet = lb[h];
    const float* wg = cw + (size_t)g * IPG * 36;

    for (int o = 0; o < IPG; ++o) {
        const float* wo = wg + o * 36;   // uniform -> s_load
        float acc = cb[g * IPG + o];
        #pragma unroll
        for (int i = 0; i < IPG; ++i)
            acc = fmaf(xm[i], wo[i*3], fmaf(xi[i], wo[i*3+1], fmaf(xp[i], wo[i*3+2], acc)));
        float gl = gelu_exact(acc + xi[o]);
        float s1 = gl, s2 = gl * gl;
        #pragma unroll
        for (int off = 32; off; off >>= 1) {
            s1 += __shfl_xor(s1, off);
            s2 += __shfl_xor(s2, off);
        }
        float mu  = s1 * (1.f / 64.f);
        float var = s2 * (1.f / 64.f) - mu * mu;
        float qn = (gl - mu) * rsqrtf(var + 1e-5f) * gam + bet;
        qo[((size_t)b * NC + g * IPG + o) * NE + h] = __float2bfloat16(qn * QSCALE);
    }
}

// ---------------------------------------------------------------------------
// Kernel 2: v = gelu(x @ fi_w^T + fi_b) via MFMA -> vT[e][c]; k from the same
// f32 x registers. grid (12, NB).
// ---------------------------------------------------------------------------
__global__ __launch_bounds__(256) void k_vk(
    const float* __restrict__ x, const float* __restrict__ fw,
    const float* __restrict__ fb, const float* __restrict__ sp,
    bf16* __restrict__ ko, bf16* __restrict__ vTo)
{
    int chunk = blockIdx.x, b = blockIdx.y;
    int tid = threadIdx.x, w = tid >> 6, l = tid & 63;
    int lr = l & 15, lc = (l >> 4) * 8;
    int rowb = chunk * 64 + w * 16;
    const float* xb = x + (size_t)b * NC * NE;

    __shared__ float sts[64];
    if (tid < 64) {
        float s = 0.f;
        #pragma unroll
        for (int p = 0; p < 16; ++p) s += sp[(size_t)(b * 16 + p) * 64 + tid];
        sts[tid] = 1.f / s;
    }

    bf16v8 bfr[4][2];
    float fbias[4];
    #pragma unroll
    for (int nt = 0; nt < 4; ++nt) {
        #pragma unroll
        for (int kt = 0; kt < 2; ++kt) {
            const float* p = fw + (nt*16 + lr) * 64 + kt*32 + lc;
            bf16v8 t;
            #pragma unroll
            for (int j = 0; j < 8; ++j) t[j] = (__bf16)p[j];
            bfr[nt][kt] = t;
        }
        fbias[nt] = fb[nt*16 + lr];
    }
    __syncthreads();

    float isA[8], isB[8];
    #pragma unroll
    for (int j = 0; j < 8; ++j) { isA[j] = sts[lc + j]; isB[j] = sts[32 + lc + j]; }

    const float* pa = xb + (size_t)(rowb + lr) * NE;
    float xa[8], xc[8];
    #pragma unroll
    for (int j = 0; j < 8; ++j) xa[j] = pa[lc + j];
    #pragma unroll
    for (int j = 0; j < 8; ++j) xc[j] = pa[32 + lc + j];

    bf16v8 a0, a1;
    #pragma unroll
    for (int j = 0; j < 8; ++j) a0[j] = (__bf16)xa[j];
    #pragma unroll
    for (int j = 0; j < 8; ++j) a1[j] = (__bf16)xc[j];

    // ---- k path from registers ----
    bf16v8 kv0, kv1;
    #pragma unroll
    for (int j = 0; j < 8; ++j) kv0[j] = (__bf16)gelu_exact(__expf(xa[j]) * isA[j]);
    #pragma unroll
    for (int j = 0; j < 8; ++j) kv1[j] = (__bf16)gelu_exact(__expf(xc[j]) * isB[j]);
    bf16* kp = ko + ((size_t)b * NC + rowb + lr) * NE + lc;
    *(bf16v8*)kp = kv0;
    *(bf16v8*)(kp + 32) = kv1;

    // ---- v MFMAs ----
    #pragma unroll
    for (int nt = 0; nt < 4; ++nt) {
        f32x4 acc = {fbias[nt], fbias[nt], fbias[nt], fbias[nt]};
        acc = MFMA16(a0, bfr[nt][0], acc);
        acc = MFMA16(a1, bfr[nt][1], acc);
        bf16v4 pk;
        #pragma unroll
        for (int r = 0; r < 4; ++r) pk[r] = (__bf16)gelu_exact(acc[r]);
        int c = rowb + (l >> 4) * 4;
        *(bf16v4*)&vTo[((size_t)b * NE + nt*16 + lr) * NC + c] = pk;
    }
}

// ---------------------------------------------------------------------------
// Kernel 3: attention, 32x32 MFMA, 3-deep counted-vmcnt pipeline + PHASE
// ROTATION: block processes k-tiles starting at offset (swz%3)*4 (softmax
// reduction is commutative -> any tile order is valid). Co-resident blocks
// on a CU are swz, swz+32, swz+64; {0,32,64} mod 3 = {0,2,1} -> the three
// blocks get distinct offsets {0,4,8}, decorrelating their staging bursts
// and stall windows (rounds 10-11: identical schedules ran phase-locked,
// MfmaUtil 16.6% == zero cross-SIMD overlap).
// Swizzles + compute identical to rounds 10-11 (verified).
// Grid 768 = 8 XCD * 96, batch-major per XCD; LDS 48 KB.
// ---------------------------------------------------------------------------
__global__ __launch_bounds__(256, 3) void k_attn(const bf16* __restrict__ qb,
                                                 const bf16* __restrict__ kb,
                                                 const bf16* __restrict__ vT,
                                                 float* __restrict__ out) {
    __shared__ __align__(16) __bf16 ldsK[3][4096];   // [buf][2 sub][32 r][64 e]
    __shared__ __align__(16) __bf16 ldsV[3][4096];   // [buf][2 sub][64 e][32 k]

    int bid = blockIdx.x;
    int swz = (bid & 7) * 96 + (bid >> 3);      // bijective: 768 = 8*96
    int b = swz / 6, qt = swz - b * 6;
    int w = threadIdx.x >> 6, l = threadIdx.x & 63;
    int q0 = qt * 128 + w * 32;
    int l31 = l & 31, b5 = l >> 5;
    int off = (swz % 3) * 4;                    // phase-rotation offset

    // staging source addresses (inverse-swizzled, rounds 7-11 verified)
    int krow_ = w * 8 + (l >> 3);
    int kc16_ = (l & 7) ^ (l >> 3);
    const char* kgbase = (const char*)(kb + (size_t)b * NC * NE)
                       + krow_ * 128 + kc16_ * 16;
    int ve_   = w * 16 + (l >> 2);
    int vc16_ = (l & 3) ^ ((l >> 3) & 3);
    const char* vgbase = (const char*)(vT + (size_t)b * NE * NC)
                       + ve_ * 1536 + vc16_ * 16;

    // read offsets (element units, within a 2048-elem subtile)
    int krd[4];
    #pragma unroll
    for (int c = 0; c < 4; ++c)
        krd[c] = l31 * 64 + ((((c << 1) | b5) ^ (l & 7)) << 3);
    int vsw = (l31 >> 1) & 3;
    int vrd[2];
    #pragma unroll
    for (int ck = 0; ck < 2; ++ck)
        vrd[ck] = l31 * 32 + ((((ck << 1) | b5) ^ vsw) << 3);

    // Q B-frags: B[col=q=l31][e-chunk c*16 + b5*8 + j]
    const bf16* qp = qb + ((size_t)b * NC + q0 + l31) * NE + b5 * 8;
    bf16v8 qf0 = *(const bf16v8*)qp;
    bf16v8 qf1 = *(const bf16v8*)(qp + 16);
    bf16v8 qf2 = *(const bf16v8*)(qp + 32);
    bf16v8 qf3 = *(const bf16v8*)(qp + 48);

    f32x16 o0 = {0,0,0,0,0,0,0,0,0,0,0,0,0,0,0,0};
    f32x16 o1 = {0,0,0,0,0,0,0,0,0,0,0,0,0,0,0,0};
    float rsum = 0.f;

    // stage(t) -> 4 gloads into buf: K sub0/sub1, V sub0/sub1 (t = k-tile idx)
    #define STAGE(t, buf)                                                     \
        do {                                                                  \
            const char* kg_ = kgbase + (size_t)(2 * (t)) * 4096;              \
            gload_lds16(kg_,        &ldsK[buf][w * 512]);                     \
            gload_lds16(kg_ + 4096, &ldsK[buf][2048 + w * 512]);              \
            const char* vg_ = vgbase + (size_t)(2 * (t)) * 64;                \
            gload_lds16(vg_,        &ldsV[buf][w * 512]);                     \
            gload_lds16(vg_ + 64,   &ldsV[buf][2048 + w * 512]);              \
        } while (0)

    // prologue: stage rotated tiles off, off+1
    int t1 = off + 1; if (t1 >= 12) t1 -= 12;
    STAGE(off, 0);
    STAGE(t1, 1);

    int cur = 0;        // buf index rotates with iteration i (not tile idx)
    for (int i = 0; i < 12; ++i) {
        if (i <= 9) {
            int ts = i + off + 2; if (ts >= 12) ts -= 12;    // max 19 -> ok
            int nbuf = (cur + 2 >= 3) ? cur - 1 : cur + 2;   // (i+2)%3
            STAGE(ts, nbuf);
            asm volatile("s_waitcnt vmcnt(8)" ::: "memory");
        } else if (i == 10) {
            asm volatile("s_waitcnt vmcnt(4)" ::: "memory");
        } else {
            asm volatile("s_waitcnt vmcnt(0)" ::: "memory");
        }
        __builtin_amdgcn_s_barrier();   // all waves' stage(i) complete

        #pragma unroll
        for (int sub = 0; sub < 2; ++sub) {
            const __bf16* Kc = &ldsK[cur][sub * 2048];
            const __bf16* Vc = &ldsV[cur][sub * 2048];

            // ---- S = K x Q^T (32k x 32q), contraction e=64 in 4 chunks ----
            bf16v8 ka0 = *(const bf16v8*)&Kc[krd[0]];
            bf16v8 ka1 = *(const bf16v8*)&Kc[krd[1]];
            bf16v8 ka2 = *(const bf16v8*)&Kc[krd[2]];
            bf16v8 ka3 = *(const bf16v8*)&Kc[krd[3]];
            __builtin_amdgcn_s_setprio(1);
            f32x16 s = {0,0,0,0,0,0,0,0,0,0,0,0,0,0,0,0};
            s = MFMA32(ka0, qf0, s);
            s = MFMA32(ka1, qf1, s);
            s = MFMA32(ka2, qf2, s);
            s = MFMA32(ka3, qf3, s);
            __builtin_amdgcn_s_setprio(0);

            // ---- softmax numerators: p = exp2(S); pack to bf16 pairs ----
            u32 wv[8];
            #pragma unroll
            for (int qd = 0; qd < 4; ++qd) {
                float a0 = exp2f(s[4*qd + 0]);
                float a1 = exp2f(s[4*qd + 1]);
                float a2 = exp2f(s[4*qd + 2]);
                float a3 = exp2f(s[4*qd + 3]);
                rsum += (a0 + a1) + (a2 + a3);
                wv[2*qd]     = pkbf(a0, a1);
                wv[2*qd + 1] = pkbf(a2, a3);
            }

            // ---- PV: O^T += V^T x P; B-frag via lane<->lane^32 exchange ----
            #pragma unroll
            for (int ck = 0; ck < 2; ++ck) {
                u32 y1 = (u32)__shfl_xor((int)(b5 ? wv[4*ck]     : wv[4*ck+2]), 32);
                u32 y2 = (u32)__shfl_xor((int)(b5 ? wv[4*ck + 1] : wv[4*ck+3]), 32);
                u32x4 fw_;
                fw_[0] = b5 ? y1 : wv[4*ck];
                fw_[1] = b5 ? y2 : wv[4*ck + 1];
                fw_[2] = b5 ? wv[4*ck + 2] : y1;
                fw_[3] = b5 ? wv[4*ck + 3] : y2;
                bf16v8 pf = __builtin_bit_cast(bf16v8, fw_);
                bf16v8 va0 = *(const bf16v8*)&Vc[vrd[ck]];
                bf16v8 va1 = *(const bf16v8*)&Vc[vrd[ck] + 1024];
                __builtin_amdgcn_s_setprio(1);
                o0 = MFMA32(va0, pf, o0);
                o1 = MFMA32(va1, pf, o1);
                __builtin_amdgcn_s_setprio(0);
            }
        }

        __builtin_amdgcn_s_barrier();   // reads of buf[cur] done before
        cur = (cur >= 2) ? 0 : cur + 1; // stage(i+3) overwrites it
    }
    #undef STAGE

    // denom: lane has the b5-half of every k-tile for q=l31; partner has rest
    rsum += __shfl_xor(rsum, 32);
    float inv = 1.f / rsum;

    // store: O^T[e][q=l31]; e = et*32 + 8*qd + 4*b5 + r (r=0..3 consecutive)
    float* ob = out + ((size_t)b * NC + q0 + l31) * NE + b5 * 4;
    #pragma unroll
    for (int qd = 0; qd < 4; ++qd) {
        f32x4 v0, v1;
        #pragma unroll
        for (int r = 0; r < 4; ++r) {
            v0[r] = o0[4*qd + r] * inv;
            v1[r] = o1[4*qd + r] * inv;
        }
        *(f32x4*)&ob[qd * 8]      = v0;
        *(f32x4*)&ob[32 + qd * 8] = v1;
    }
}

// ---------------------------------------------------------------------------
extern "C" void kernel_launch(void* const* d_in, const int* in_sizes, int n_in,
                              void* d_out, int out_size, void* d_ws, size_t ws_size,
                              hipStream_t stream) {
    (void)in_sizes; (void)n_in; (void)out_size; (void)ws_size;
    const float* x      = (const float*)d_in[0];
    const float* conv_w = (const float*)d_in[1];
    const float* conv_b = (const float*)d_in[2];
    const float* ln_g   = (const float*)d_in[3];
    const float* ln_b   = (const float*)d_in[4];
    const float* fi_w   = (const float*)d_in[5];
    const float* fi_b   = (const float*)d_in[6];
    // bi_w/bi_b unused: mask is constant along softmax axis -> exact no-op.

    bf16* qbuf = (bf16*)d_ws;
    bf16* kbuf = qbuf + (size_t)NB * NC * NE;
    bf16* vT   = kbuf + (size_t)NB * NC * NE;
    float* stats = (float*)(vT + (size_t)NB * NC * NE);   // NB*16*64 f32
    float* out = (float*)d_out;

    k_conv<<<dim3(NB * 16), 256, 0, stream>>>(x, conv_w, conv_b, ln_g, ln_b,
                                              qbuf, stats);
    k_vk<<<dim3(12, NB), 256, 0, stream>>>(x, fi_w, fi_b, stats, kbuf, vT);
    k_attn<<<dim3(768), 256, 0, stream>>>(qbuf, kbuf, vT, out);
}

// Round 13
// 82.738 us; speedup vs baseline: 1.0011x; 1.0011x over previous
//
#include <hip/hip_runtime.h>
#include <hip/hip_bf16.h>
#include <math.h>

#define NB 128    // batches after reshape
#define NC 768    // channels (rows)
#define NE 64     // inner dim (cols)
#define IPG 12    // channels per conv group

// q pre-scale: 1/8 (SDPA) * log2(e) so attn softmax is exp2(S) on v_exp_f32
#define QSCALE 0.18033688011112042f

typedef __hip_bfloat16 bf16;
typedef __bf16 bf16v8 __attribute__((ext_vector_type(8)));
typedef __bf16 bf16v4 __attribute__((ext_vector_type(4)));
typedef __bf16 bf16v2 __attribute__((ext_vector_type(2)));
typedef float f32x4 __attribute__((ext_vector_type(4)));
typedef unsigned int u32;
typedef u32 u32x4 __attribute__((ext_vector_type(4)));

// gelu = x * Phi(x); Phi via Abramowitz-Stegun 26.2.17 (|err| < 7.5e-8).
__device__ __forceinline__ float gelu_exact(float x) {
    float ax = fabsf(x);
    float t = __builtin_amdgcn_rcpf(fmaf(0.2316419f, ax, 1.0f));
    float poly = t * fmaf(t, fmaf(t, fmaf(t, fmaf(t, 1.330274429f,
                  -1.821255978f), 1.781477937f), -0.356563782f), 0.319381530f);
    float pdf = 0.3989422804f * __expf(-0.5f * ax * ax);
    float c = fmaf(-pdf, poly, 1.0f);
    float cdf = (x >= 0.f) ? c : 1.0f - c;
    return x * cdf;
}

#define MFMA16(a, b, c) __builtin_amdgcn_mfma_f32_16x16x32_bf16(a, b, c, 0, 0, 0)

__device__ __forceinline__ void gload_lds16(const void* g, void* l) {
    __builtin_amdgcn_global_load_lds(
        (const __attribute__((address_space(1))) void*)g,
        (__attribute__((address_space(3))) void*)l, 16, 0, 0);
}

// ---------------------------------------------------------------------------
// Kernel 1: q path (conv+res+gelu+LN, pre-scaled) + column exp-sum partials.
// ---------------------------------------------------------------------------
__global__ __launch_bounds__(256) void k_conv(
    const float* __restrict__ x, const float* __restrict__ cw,
    const float* __restrict__ cb, const float* __restrict__ lg,
    const float* __restrict__ lb, bf16* __restrict__ qo,
    float* __restrict__ sp)
{
    int b = blockIdx.x >> 4;
    int chunk = blockIdx.x & 15;
    int w = threadIdx.x >> 6;
    int g = __builtin_amdgcn_readfirstlane(chunk * 4 + w);   // wave-uniform
    int h = threadIdx.x & 63;
    const float* xb = x + ((size_t)b * NC + g * IPG) * NE;

    float xi[IPG], xm[IPG], xp[IPG];
    #pragma unroll
    for (int i = 0; i < IPG; ++i) {
        xi[i] = xb[i * NE + h];
        float up = __shfl_up(xi[i], 1);
        float dn = __shfl_down(xi[i], 1);
        xm[i] = h ? up : 0.f;
        xp[i] = (h < 63) ? dn : 0.f;
    }

    // column exp-sum partial over this block's 48 rows
    float es = 0.f;
    #pragma unroll
    for (int i = 0; i < IPG; ++i) es += __expf(xi[i]);
    __shared__ float red[4][64];
    red[w][h] = es;
    __syncthreads();
    if (w == 0) {
        float s = red[0][h] + red[1][h] + red[2][h] + red[3][h];
        sp[(size_t)(b * 16 + chunk) * 64 + h] = s;
    }

    float gam = lg[h], bet = lb[h];
    const float* wg = cw + (size_t)g * IPG * 36;

    for (int o = 0; o < IPG; ++o) {
        const float* wo = wg + o * 36;   // uniform -> s_load
        float acc = cb[g * IPG + o];
        #pragma unroll
        for (int i = 0; i < IPG; ++i)
            acc = fmaf(xm[i], wo[i*3], fmaf(xi[i], wo[i*3+1], fmaf(xp[i], wo[i*3+2], acc)));
        float gl = gelu_exact(acc + xi[o]);
        float s1 = gl, s2 = gl * gl;
        #pragma unroll
        for (int off = 32; off; off >>= 1) {
            s1 += __shfl_xor(s1, off);
            s2 += __shfl_xor(s2, off);
        }
        float mu  = s1 * (1.f / 64.f);
        float var = s2 * (1.f / 64.f) - mu * mu;
        float qn = (gl - mu) * rsqrtf(var + 1e-5f) * gam + bet;
        qo[((size_t)b * NC + g * IPG + o) * NE + h] = __float2bfloat16(qn * QSCALE);
    }
}

// ---------------------------------------------------------------------------
// Kernel 2: v = gelu(x @ fi_w^T + fi_b) via MFMA; k from the same f32 x regs.
// V now stored TILED: vt2[b][kt][e][kc] (kt = k/32, kc = k%32) so each 32-k
// V tile is 4 KB CONTIGUOUS -> k_attn's V staging is coalesced (was a 16x64B
// gather at stride 1536B). Write scatter here is unchanged vs old layout.
// ---------------------------------------------------------------------------
__global__ __launch_bounds__(256) void k_vk(
    const float* __restrict__ x, const float* __restrict__ fw,
    const float* __restrict__ fb, const float* __restrict__ sp,
    bf16* __restrict__ ko, bf16* __restrict__ vt2)
{
    int chunk = blockIdx.x, b = blockIdx.y;
    int tid = threadIdx.x, w = tid >> 6, l = tid & 63;
    int lr = l & 15, lc = (l >> 4) * 8;
    int rowb = chunk * 64 + w * 16;
    const float* xb = x + (size_t)b * NC * NE;

    __shared__ float sts[64];
    if (tid < 64) {
        float s = 0.f;
        #pragma unroll
        for (int p = 0; p < 16; ++p) s += sp[(size_t)(b * 16 + p) * 64 + tid];
        sts[tid] = 1.f / s;
    }

    bf16v8 bfr[4][2];
    float fbias[4];
    #pragma unroll
    for (int nt = 0; nt < 4; ++nt) {
        #pragma unroll
        for (int kt = 0; kt < 2; ++kt) {
            const float* p = fw + (nt*16 + lr) * 64 + kt*32 + lc;
            bf16v8 t;
            #pragma unroll
            for (int j = 0; j < 8; ++j) t[j] = (__bf16)p[j];
            bfr[nt][kt] = t;
        }
        fbias[nt] = fb[nt*16 + lr];
    }
    __syncthreads();

    float isA[8], isB[8];
    #pragma unroll
    for (int j = 0; j < 8; ++j) { isA[j] = sts[lc + j]; isB[j] = sts[32 + lc + j]; }

    const float* pa = xb + (size_t)(rowb + lr) * NE;
    float xa[8], xc[8];
    #pragma unroll
    for (int j = 0; j < 8; ++j) xa[j] = pa[lc + j];
    #pragma unroll
    for (int j = 0; j < 8; ++j) xc[j] = pa[32 + lc + j];

    bf16v8 a0, a1;
    #pragma unroll
    for (int j = 0; j < 8; ++j) a0[j] = (__bf16)xa[j];
    #pragma unroll
    for (int j = 0; j < 8; ++j) a1[j] = (__bf16)xc[j];

    // ---- k path from registers ----
    bf16v8 kv0, kv1;
    #pragma unroll
    for (int j = 0; j < 8; ++j) kv0[j] = (__bf16)gelu_exact(__expf(xa[j]) * isA[j]);
    #pragma unroll
    for (int j = 0; j < 8; ++j) kv1[j] = (__bf16)gelu_exact(__expf(xc[j]) * isB[j]);
    bf16* kp = ko + ((size_t)b * NC + rowb + lr) * NE + lc;
    *(bf16v8*)kp = kv0;
    *(bf16v8*)(kp + 32) = kv1;

    // ---- v MFMAs -> tiled store ----
    int c0 = rowb + (l >> 4) * 4;          // 4 consecutive k-rows, same tile
    int ktile = c0 >> 5, kc = c0 & 31;
    #pragma unroll
    for (int nt = 0; nt < 4; ++nt) {
        f32x4 acc = {fbias[nt], fbias[nt], fbias[nt], fbias[nt]};
        acc = MFMA16(a0, bfr[nt][0], acc);
        acc = MFMA16(a1, bfr[nt][1], acc);
        bf16v4 pk;
        #pragma unroll
        for (int r = 0; r < 4; ++r) pk[r] = (__bf16)gelu_exact(acc[r]);
        *(bf16v4*)&vt2[(((size_t)b * 24 + ktile) * 64 + nt*16 + lr) * 32 + kc] = pk;
    }
}

// ---------------------------------------------------------------------------
// softmax + P-redistribution for one 16-q tile (verified mapping, rounds 3-9):
// lane holds S[k-frag rows][q=lr]; returns PV A-frag P[q=lr][k chunk hi*8..+7].
// exp2-based (q pre-scaled by QSCALE).
// ---------------------------------------------------------------------------
__device__ __forceinline__ bf16v8 softmax_exch(f32x4 s0, f32x4 s1, float& rsum,
                                               int srcA, int srcB, int hq) {
    float p0 = exp2f(s0[0]), p1 = exp2f(s0[1]), p2 = exp2f(s0[2]), p3 = exp2f(s0[3]);
    float p4 = exp2f(s1[0]), p5 = exp2f(s1[1]), p6 = exp2f(s1[2]), p7 = exp2f(s1[3]);
    rsum += ((p0 + p1) + (p2 + p3)) + ((p4 + p5) + (p6 + p7));
    bf16v2 t0; t0[0] = (__bf16)p0; t0[1] = (__bf16)p1;
    bf16v2 t1; t1[0] = (__bf16)p2; t1[1] = (__bf16)p3;
    bf16v2 t2; t2[0] = (__bf16)p4; t2[1] = (__bf16)p5;
    bf16v2 t3; t3[0] = (__bf16)p6; t3[1] = (__bf16)p7;
    u32 w0 = __builtin_bit_cast(u32, t0), w1 = __builtin_bit_cast(u32, t1);
    u32 w2 = __builtin_bit_cast(u32, t2), w3 = __builtin_bit_cast(u32, t3);
    u32 c0A = (u32)__shfl((int)w0, srcA), c1A = (u32)__shfl((int)w1, srcA);
    u32 c2A = (u32)__shfl((int)w2, srcA), c3A = (u32)__shfl((int)w3, srcA);
    u32 c0B = (u32)__shfl((int)w0, srcB), c1B = (u32)__shfl((int)w1, srcB);
    u32 c2B = (u32)__shfl((int)w2, srcB), c3B = (u32)__shfl((int)w3, srcB);
    u32x4 pau = { hq ? c2A : c0A, hq ? c3A : c1A,
                  hq ? c2B : c0B, hq ? c3B : c1B };
    return __builtin_bit_cast(bf16v8, pau);
}

// ---------------------------------------------------------------------------
// Kernel 3: attention — round-8 16x16 structure (measured faster than the
// 32x32 body by ~4 us) + TILED V staging (contiguous 4 KB tiles; the old
// layout made each V global_load_lds a 16-segment gather, a TA-throughput
// cost no pipeline depth can hide — rounds 10-12 nulls).
// 2-buf BK=64, syncthreads drain, setprio, swizzles verified rounds 7-9.
// Grid 768 = 8 XCD * 96, batch-major per XCD; LDS 32 KB; 3 blocks/CU.
// ---------------------------------------------------------------------------
__global__ __launch_bounds__(256, 3) void k_attn(const bf16* __restrict__ qb,
                                                 const bf16* __restrict__ kb,
                                                 const bf16* __restrict__ vt2,
                                                 float* __restrict__ out) {
    __shared__ __align__(16) __bf16 ldsK[2][4096];   // [buf][2 sub][32 r][64 e]
    __shared__ __align__(16) __bf16 ldsV[2][4096];   // [buf][2 sub][64 e][32 k]

    int bid = blockIdx.x;
    int swz = (bid & 7) * 96 + (bid >> 3);      // bijective: 768 = 8*96
    int b = swz / 6, qt = swz - b * 6;
    int w = threadIdx.x >> 6, l = threadIdx.x & 63;
    int q0 = qt * 128 + w * 32;
    int lr = l & 15, hi = l >> 4;
    int hq = hi >> 1;
    int srcA = lr + ((hi & 1) << 5);
    int srcB = srcA + 16;

    // staging source addresses (inverse-swizzled; K unchanged, V tiled)
    int krow_ = w * 8 + (l >> 3);
    int kc16_ = (l & 7) ^ (l >> 3);
    const char* kgbase = (const char*)(kb + (size_t)b * NC * NE)
                       + krow_ * 128 + kc16_ * 16;
    int ve_   = w * 16 + (l >> 2);
    int vc16_ = (l & 3) ^ ((l >> 3) & 3);    // (e>>1)&3 == (l>>3)&3, invariant
    const char* vgbase = (const char*)vt2 + (size_t)b * 24 * 4096
                       + ve_ * 64 + vc16_ * 16;

    // swizzled ds_read element offsets (within a 2048-elem subtile)
    int krd0 = lr * 64 + ((hi ^ (lr & 7)) << 3);
    int krd1 = lr * 64 + (((4 + hi) ^ (lr & 7)) << 3);
    int vsel = (lr >> 1) & 3;
    int vrd  = lr * 32 + ((hi ^ vsel) << 3);

    const bf16* qp = qb + ((size_t)b * NC + q0 + lr) * NE + hi * 8;
    bf16v8 qf00 = *(const bf16v8*)qp;
    bf16v8 qf01 = *(const bf16v8*)(qp + 32);
    bf16v8 qf10 = *(const bf16v8*)(qp + 16 * NE);
    bf16v8 qf11 = *(const bf16v8*)(qp + 16 * NE + 32);

    f32x4 o00 = {0,0,0,0}, o01 = {0,0,0,0}, o02 = {0,0,0,0}, o03 = {0,0,0,0};
    f32x4 o10 = {0,0,0,0}, o11 = {0,0,0,0}, o12 = {0,0,0,0}, o13 = {0,0,0,0};
    float rsum0 = 0.f, rsum1 = 0.f;

    // prologue: stage k-tiles 0,1 into buf 0 (V tile stride now 4096 B)
    gload_lds16(kgbase,        &ldsK[0][w * 512]);
    gload_lds16(kgbase + 4096, &ldsK[0][2048 + w * 512]);
    gload_lds16(vgbase,        &ldsV[0][w * 512]);
    gload_lds16(vgbase + 4096, &ldsV[0][2048 + w * 512]);
    __syncthreads();

    int cur = 0;
    for (int ph = 0; ph < 12; ++ph) {
        if (ph < 11) {   // stage k-tiles 2ph+2, 2ph+3 into the other buffer
            const char* kg = kgbase + (size_t)(2 * ph + 2) * 4096;
            gload_lds16(kg,        &ldsK[cur ^ 1][w * 512]);
            gload_lds16(kg + 4096, &ldsK[cur ^ 1][2048 + w * 512]);
            const char* vg = vgbase + (size_t)(2 * ph + 2) * 4096;
            gload_lds16(vg,        &ldsV[cur ^ 1][w * 512]);
            gload_lds16(vg + 4096, &ldsV[cur ^ 1][2048 + w * 512]);
        }

        #pragma unroll
        for (int sub = 0; sub < 2; ++sub) {
            const __bf16* Kc = &ldsK[cur][sub * 2048];
            const __bf16* Vc = &ldsV[cur][sub * 2048];
            bf16v8 ka0 = *(const bf16v8*)&Kc[krd0];
            bf16v8 ka1 = *(const bf16v8*)&Kc[krd1];
            bf16v8 ka2 = *(const bf16v8*)&Kc[krd0 + 1024];
            bf16v8 ka3 = *(const bf16v8*)&Kc[krd1 + 1024];
            bf16v8 v0  = *(const bf16v8*)&Vc[vrd];
            bf16v8 v1  = *(const bf16v8*)&Vc[vrd + 512];
            bf16v8 v2  = *(const bf16v8*)&Vc[vrd + 1024];
            bf16v8 v3  = *(const bf16v8*)&Vc[vrd + 1536];

            __builtin_amdgcn_s_setprio(1);
            f32x4 s00 = {0,0,0,0}, s01 = {0,0,0,0};
            s00 = MFMA16(ka0, qf00, s00);
            s00 = MFMA16(ka1, qf01, s00);
            s01 = MFMA16(ka2, qf00, s01);
            s01 = MFMA16(ka3, qf01, s01);
            f32x4 s10 = {0,0,0,0}, s11 = {0,0,0,0};
            s10 = MFMA16(ka0, qf10, s10);
            s10 = MFMA16(ka1, qf11, s10);
            s11 = MFMA16(ka2, qf10, s11);
            s11 = MFMA16(ka3, qf11, s11);
            __builtin_amdgcn_s_setprio(0);

            bf16v8 pa0 = softmax_exch(s00, s01, rsum0, srcA, srcB, hq);
            bf16v8 pa1 = softmax_exch(s10, s11, rsum1, srcA, srcB, hq);

            __builtin_amdgcn_s_setprio(1);
            o00 = MFMA16(pa0, v0, o00);
            o01 = MFMA16(pa0, v1, o01);
            o02 = MFMA16(pa0, v2, o02);
            o03 = MFMA16(pa0, v3, o03);
            o10 = MFMA16(pa1, v0, o10);
            o11 = MFMA16(pa1, v1, o11);
            o12 = MFMA16(pa1, v2, o12);
            o13 = MFMA16(pa1, v3, o13);
            __builtin_amdgcn_s_setprio(0);
        }

        __syncthreads();   // drains staging vmcnt; flips buffers safely
        cur ^= 1;
    }

    rsum0 += __shfl_xor(rsum0, 16);
    rsum0 += __shfl_xor(rsum0, 32);
    rsum1 += __shfl_xor(rsum1, 16);
    rsum1 += __shfl_xor(rsum1, 32);
    float inv0 = 1.f / rsum0, inv1 = 1.f / rsum1;

    int qrow0 = q0 + hi * 4;
    #pragma unroll
    for (int r = 0; r < 4; ++r) {
        float iq = __shfl(inv0, hi * 4 + r);
        float* op = out + ((size_t)b * NC + qrow0 + r) * NE + lr;
        op[0]  = o00[r] * iq;
        op[16] = o01[r] * iq;
        op[32] = o02[r] * iq;
        op[48] = o03[r] * iq;
    }
    int qrow1 = q0 + 16 + hi * 4;
    #pragma unroll
    for (int r = 0; r < 4; ++r) {
        float iq = __shfl(inv1, hi * 4 + r);
        float* op = out + ((size_t)b * NC + qrow1 + r) * NE + lr;
        op[0]  = o10[r] * iq;
        op[16] = o11[r] * iq;
        op[32] = o12[r] * iq;
        op[48] = o13[r] * iq;
    }
}

// ---------------------------------------------------------------------------
extern "C" void kernel_launch(void* const* d_in, const int* in_sizes, int n_in,
                              void* d_out, int out_size, void* d_ws, size_t ws_size,
                              hipStream_t stream) {
    (void)in_sizes; (void)n_in; (void)out_size; (void)ws_size;
    const float* x      = (const float*)d_in[0];
    const float* conv_w = (const float*)d_in[1];
    const float* conv_b = (const float*)d_in[2];
    const float* ln_g   = (const float*)d_in[3];
    const float* ln_b   = (const float*)d_in[4];
    const float* fi_w   = (const float*)d_in[5];
    const float* fi_b   = (const float*)d_in[6];
    // bi_w/bi_b unused: mask is constant along softmax axis -> exact no-op.

    bf16* qbuf = (bf16*)d_ws;
    bf16* kbuf = qbuf + (size_t)NB * NC * NE;
    bf16* vt2  = kbuf + (size_t)NB * NC * NE;             // tiled V
    float* stats = (float*)(vt2 + (size_t)NB * NC * NE);  // NB*16*64 f32
    float* out = (float*)d_out;

    k_conv<<<dim3(NB * 16), 256, 0, stream>>>(x, conv_w, conv_b, ln_g, ln_b,
                                              qbuf, stats);
    k_vk<<<dim3(12, NB), 256, 0, stream>>>(x, fi_w, fi_b, stats, kbuf, vt2);
    k_attn<<<dim3(768), 256, 0, stream>>>(qbuf, kbuf, vt2, out);
}

// Round 14
// 78.191 us; speedup vs baseline: 1.0593x; 1.0582x over previous
//
#include <hip/hip_runtime.h>
#include <hip/hip_bf16.h>
#include <math.h>

#define NB 128    // batches after reshape
#define NC 768    // channels (rows)
#define NE 64     // inner dim (cols)
#define IPG 12    // channels per conv group

typedef __hip_bfloat16 bf16;
typedef __bf16 bf16v8 __attribute__((ext_vector_type(8)));
typedef __bf16 bf16v4 __attribute__((ext_vector_type(4)));
typedef __bf16 bf16v2 __attribute__((ext_vector_type(2)));
typedef float f32x4 __attribute__((ext_vector_type(4)));
typedef unsigned int u32;
typedef u32 u32x4 __attribute__((ext_vector_type(4)));

// gelu = x * Phi(x); Phi via Abramowitz-Stegun 26.2.17 (|err| < 7.5e-8).
__device__ __forceinline__ float gelu_exact(float x) {
    float ax = fabsf(x);
    float t = __builtin_amdgcn_rcpf(fmaf(0.2316419f, ax, 1.0f));
    float poly = t * fmaf(t, fmaf(t, fmaf(t, fmaf(t, 1.330274429f,
                  -1.821255978f), 1.781477937f), -0.356563782f), 0.319381530f);
    float pdf = 0.3989422804f * __expf(-0.5f * ax * ax);
    float c = fmaf(-pdf, poly, 1.0f);
    float cdf = (x >= 0.f) ? c : 1.0f - c;
    return x * cdf;
}

#define MFMA16(a, b, c) __builtin_amdgcn_mfma_f32_16x16x32_bf16(a, b, c, 0, 0, 0)

__device__ __forceinline__ void gload_lds16(const void* g, void* l) {
    __builtin_amdgcn_global_load_lds(
        (const __attribute__((address_space(1))) void*)g,
        (__attribute__((address_space(3))) void*)l, 16, 0, 0);
}

// ---------------------------------------------------------------------------
// Kernel 1: q path (conv+res+gelu+LN, pre-scaled 0.125) + column exp-sums.
// ---------------------------------------------------------------------------
__global__ __launch_bounds__(256) void k_conv(
    const float* __restrict__ x, const float* __restrict__ cw,
    const float* __restrict__ cb, const float* __restrict__ lg,
    const float* __restrict__ lb, bf16* __restrict__ qo,
    float* __restrict__ sp)
{
    int b = blockIdx.x >> 4;
    int chunk = blockIdx.x & 15;
    int w = threadIdx.x >> 6;
    int g = __builtin_amdgcn_readfirstlane(chunk * 4 + w);   // wave-uniform
    int h = threadIdx.x & 63;
    const float* xb = x + ((size_t)b * NC + g * IPG) * NE;

    float xi[IPG], xm[IPG], xp[IPG];
    #pragma unroll
    for (int i = 0; i < IPG; ++i) {
        xi[i] = xb[i * NE + h];
        float up = __shfl_up(xi[i], 1);
        float dn = __shfl_down(xi[i], 1);
        xm[i] = h ? up : 0.f;
        xp[i] = (h < 63) ? dn : 0.f;
    }

    // column exp-sum partial over this block's 48 rows
    float es = 0.f;
    #pragma unroll
    for (int i = 0; i < IPG; ++i) es += __expf(xi[i]);
    __shared__ float red[4][64];
    red[w][h] = es;
    __syncthreads();
    if (w == 0) {
        float s = red[0][h] + red[1][h] + red[2][h] + red[3][h];
        sp[(size_t)(b * 16 + chunk) * 64 + h] = s;
    }

    float gam = lg[h], bet = lb[h];
    const float* wg = cw + (size_t)g * IPG * 36;

    for (int o = 0; o < IPG; ++o) {
        const float* wo = wg + o * 36;   // uniform -> s_load
        float acc = cb[g * IPG + o];
        #pragma unroll
        for (int i = 0; i < IPG; ++i)
            acc = fmaf(xm[i], wo[i*3], fmaf(xi[i], wo[i*3+1], fmaf(xp[i], wo[i*3+2], acc)));
        float gl = gelu_exact(acc + xi[o]);
        float s1 = gl, s2 = gl * gl;
        #pragma unroll
        for (int off = 32; off; off >>= 1) {
            s1 += __shfl_xor(s1, off);
            s2 += __shfl_xor(s2, off);
        }
        float mu  = s1 * (1.f / 64.f);
        float var = s2 * (1.f / 64.f) - mu * mu;
        float qn = (gl - mu) * rsqrtf(var + 1e-5f) * gam + bet;
        qo[((size_t)b * NC + g * IPG + o) * NE + h] = __float2bfloat16(qn * 0.125f);
    }
}

// ---------------------------------------------------------------------------
// Kernel 2: v = gelu(x @ fi_w^T + fi_b) via MFMA; k from the same f32 x regs.
// V stored TILED: vt2[b][kt][e][kc] -> each 32-k V tile is 4 KB contiguous.
// ---------------------------------------------------------------------------
__global__ __launch_bounds__(256) void k_vk(
    const float* __restrict__ x, const float* __restrict__ fw,
    const float* __restrict__ fb, const float* __restrict__ sp,
    bf16* __restrict__ ko, bf16* __restrict__ vt2)
{
    int chunk = blockIdx.x, b = blockIdx.y;
    int tid = threadIdx.x, w = tid >> 6, l = tid & 63;
    int lr = l & 15, lc = (l >> 4) * 8;
    int rowb = chunk * 64 + w * 16;
    const float* xb = x + (size_t)b * NC * NE;

    __shared__ float sts[64];
    if (tid < 64) {
        float s = 0.f;
        #pragma unroll
        for (int p = 0; p < 16; ++p) s += sp[(size_t)(b * 16 + p) * 64 + tid];
        sts[tid] = 1.f / s;
    }

    bf16v8 bfr[4][2];
    float fbias[4];
    #pragma unroll
    for (int nt = 0; nt < 4; ++nt) {
        #pragma unroll
        for (int kt = 0; kt < 2; ++kt) {
            const float* p = fw + (nt*16 + lr) * 64 + kt*32 + lc;
            bf16v8 t;
            #pragma unroll
            for (int j = 0; j < 8; ++j) t[j] = (__bf16)p[j];
            bfr[nt][kt] = t;
        }
        fbias[nt] = fb[nt*16 + lr];
    }
    __syncthreads();

    float isA[8], isB[8];
    #pragma unroll
    for (int j = 0; j < 8; ++j) { isA[j] = sts[lc + j]; isB[j] = sts[32 + lc + j]; }

    const float* pa = xb + (size_t)(rowb + lr) * NE;
    float xa[8], xc[8];
    #pragma unroll
    for (int j = 0; j < 8; ++j) xa[j] = pa[lc + j];
    #pragma unroll
    for (int j = 0; j < 8; ++j) xc[j] = pa[32 + lc + j];

    bf16v8 a0, a1;
    #pragma unroll
    for (int j = 0; j < 8; ++j) a0[j] = (__bf16)xa[j];
    #pragma unroll
    for (int j = 0; j < 8; ++j) a1[j] = (__bf16)xc[j];

    // ---- k path from registers ----
    bf16v8 kv0, kv1;
    #pragma unroll
    for (int j = 0; j < 8; ++j) kv0[j] = (__bf16)gelu_exact(__expf(xa[j]) * isA[j]);
    #pragma unroll
    for (int j = 0; j < 8; ++j) kv1[j] = (__bf16)gelu_exact(__expf(xc[j]) * isB[j]);
    bf16* kp = ko + ((size_t)b * NC + rowb + lr) * NE + lc;
    *(bf16v8*)kp = kv0;
    *(bf16v8*)(kp + 32) = kv1;

    // ---- v MFMAs -> tiled store ----
    int c0 = rowb + (l >> 4) * 4;          // 4 consecutive k-rows, same tile
    int ktile = c0 >> 5, kc = c0 & 31;
    #pragma unroll
    for (int nt = 0; nt < 4; ++nt) {
        f32x4 acc = {fbias[nt], fbias[nt], fbias[nt], fbias[nt]};
        acc = MFMA16(a0, bfr[nt][0], acc);
        acc = MFMA16(a1, bfr[nt][1], acc);
        bf16v4 pk;
        #pragma unroll
        for (int r = 0; r < 4; ++r) pk[r] = (__bf16)gelu_exact(acc[r]);
        *(bf16v4*)&vt2[(((size_t)b * 24 + ktile) * 64 + nt*16 + lr) * 32 + kc] = pk;
    }
}

// ---------------------------------------------------------------------------
// softmax + P-redistribution for one 16-q tile (verified mapping, rounds 3-9):
// lane holds S[k-frag rows][q=lr]; returns PV A-frag P[q=lr][k chunk hi*8..+7].
// __expf on pre-scaled (0.125) scores — the FAST ocml path (mul+v_exp).
// [r13 lesson: libm exp2f is NOT the fast path; it cost ~4 us since r10.]
// ---------------------------------------------------------------------------
__device__ __forceinline__ bf16v8 softmax_exch(f32x4 s0, f32x4 s1, float& rsum,
                                               int srcA, int srcB, int hq) {
    float p0 = __expf(s0[0]), p1 = __expf(s0[1]), p2 = __expf(s0[2]), p3 = __expf(s0[3]);
    float p4 = __expf(s1[0]), p5 = __expf(s1[1]), p6 = __expf(s1[2]), p7 = __expf(s1[3]);
    rsum += ((p0 + p1) + (p2 + p3)) + ((p4 + p5) + (p6 + p7));
    bf16v2 t0; t0[0] = (__bf16)p0; t0[1] = (__bf16)p1;
    bf16v2 t1; t1[0] = (__bf16)p2; t1[1] = (__bf16)p3;
    bf16v2 t2; t2[0] = (__bf16)p4; t2[1] = (__bf16)p5;
    bf16v2 t3; t3[0] = (__bf16)p6; t3[1] = (__bf16)p7;
    u32 w0 = __builtin_bit_cast(u32, t0), w1 = __builtin_bit_cast(u32, t1);
    u32 w2 = __builtin_bit_cast(u32, t2), w3 = __builtin_bit_cast(u32, t3);
    u32 c0A = (u32)__shfl((int)w0, srcA), c1A = (u32)__shfl((int)w1, srcA);
    u32 c2A = (u32)__shfl((int)w2, srcA), c3A = (u32)__shfl((int)w3, srcA);
    u32 c0B = (u32)__shfl((int)w0, srcB), c1B = (u32)__shfl((int)w1, srcB);
    u32 c2B = (u32)__shfl((int)w2, srcB), c3B = (u32)__shfl((int)w3, srcB);
    u32x4 pau = { hq ? c2A : c0A, hq ? c3A : c1A,
                  hq ? c2B : c0B, hq ? c3B : c1B };
    return __builtin_bit_cast(bf16v8, pau);
}

// ---------------------------------------------------------------------------
// Kernel 3: attention — 16x16 body, __expf softmax (round-9 config) + tiled-V
// contiguous staging. 2-buf BK=64, syncthreads drain, setprio, swizzles
// verified rounds 7-9. Grid 768 = 8 XCD * 96; LDS 32 KB; 3 blocks/CU.
// ---------------------------------------------------------------------------
__global__ __launch_bounds__(256, 3) void k_attn(const bf16* __restrict__ qb,
                                                 const bf16* __restrict__ kb,
                                                 const bf16* __restrict__ vt2,
                                                 float* __restrict__ out) {
    __shared__ __align__(16) __bf16 ldsK[2][4096];   // [buf][2 sub][32 r][64 e]
    __shared__ __align__(16) __bf16 ldsV[2][4096];   // [buf][2 sub][64 e][32 k]

    int bid = blockIdx.x;
    int swz = (bid & 7) * 96 + (bid >> 3);      // bijective: 768 = 8*96
    int b = swz / 6, qt = swz - b * 6;
    int w = threadIdx.x >> 6, l = threadIdx.x & 63;
    int q0 = qt * 128 + w * 32;
    int lr = l & 15, hi = l >> 4;
    int hq = hi >> 1;
    int srcA = lr + ((hi & 1) << 5);
    int srcB = srcA + 16;

    // staging source addresses (inverse-swizzled; K rows, V tiled 4KB)
    int krow_ = w * 8 + (l >> 3);
    int kc16_ = (l & 7) ^ (l >> 3);
    const char* kgbase = (const char*)(kb + (size_t)b * NC * NE)
                       + krow_ * 128 + kc16_ * 16;
    int ve_   = w * 16 + (l >> 2);
    int vc16_ = (l & 3) ^ ((l >> 3) & 3);
    const char* vgbase = (const char*)vt2 + (size_t)b * 24 * 4096
                       + ve_ * 64 + vc16_ * 16;

    // swizzled ds_read element offsets (within a 2048-elem subtile)
    int krd0 = lr * 64 + ((hi ^ (lr & 7)) << 3);
    int krd1 = lr * 64 + (((4 + hi) ^ (lr & 7)) << 3);
    int vsel = (lr >> 1) & 3;
    int vrd  = lr * 32 + ((hi ^ vsel) << 3);

    const bf16* qp = qb + ((size_t)b * NC + q0 + lr) * NE + hi * 8;
    bf16v8 qf00 = *(const bf16v8*)qp;
    bf16v8 qf01 = *(const bf16v8*)(qp + 32);
    bf16v8 qf10 = *(const bf16v8*)(qp + 16 * NE);
    bf16v8 qf11 = *(const bf16v8*)(qp + 16 * NE + 32);

    f32x4 o00 = {0,0,0,0}, o01 = {0,0,0,0}, o02 = {0,0,0,0}, o03 = {0,0,0,0};
    f32x4 o10 = {0,0,0,0}, o11 = {0,0,0,0}, o12 = {0,0,0,0}, o13 = {0,0,0,0};
    float rsum0 = 0.f, rsum1 = 0.f;

    // prologue: stage k-tiles 0,1 into buf 0 (V tile stride 4096 B)
    gload_lds16(kgbase,        &ldsK[0][w * 512]);
    gload_lds16(kgbase + 4096, &ldsK[0][2048 + w * 512]);
    gload_lds16(vgbase,        &ldsV[0][w * 512]);
    gload_lds16(vgbase + 4096, &ldsV[0][2048 + w * 512]);
    __syncthreads();

    int cur = 0;
    for (int ph = 0; ph < 12; ++ph) {
        if (ph < 11) {   // stage k-tiles 2ph+2, 2ph+3 into the other buffer
            const char* kg = kgbase + (size_t)(2 * ph + 2) * 4096;
            gload_lds16(kg,        &ldsK[cur ^ 1][w * 512]);
            gload_lds16(kg + 4096, &ldsK[cur ^ 1][2048 + w * 512]);
            const char* vg = vgbase + (size_t)(2 * ph + 2) * 4096;
            gload_lds16(vg,        &ldsV[cur ^ 1][w * 512]);
            gload_lds16(vg + 4096, &ldsV[cur ^ 1][2048 + w * 512]);
        }

        #pragma unroll
        for (int sub = 0; sub < 2; ++sub) {
            const __bf16* Kc = &ldsK[cur][sub * 2048];
            const __bf16* Vc = &ldsV[cur][sub * 2048];
            bf16v8 ka0 = *(const bf16v8*)&Kc[krd0];
            bf16v8 ka1 = *(const bf16v8*)&Kc[krd1];
            bf16v8 ka2 = *(const bf16v8*)&Kc[krd0 + 1024];
            bf16v8 ka3 = *(const bf16v8*)&Kc[krd1 + 1024];
            bf16v8 v0  = *(const bf16v8*)&Vc[vrd];
            bf16v8 v1  = *(const bf16v8*)&Vc[vrd + 512];
            bf16v8 v2  = *(const bf16v8*)&Vc[vrd + 1024];
            bf16v8 v3  = *(const bf16v8*)&Vc[vrd + 1536];

            __builtin_amdgcn_s_setprio(1);
            f32x4 s00 = {0,0,0,0}, s01 = {0,0,0,0};
            s00 = MFMA16(ka0, qf00, s00);
            s00 = MFMA16(ka1, qf01, s00);
            s01 = MFMA16(ka2, qf00, s01);
            s01 = MFMA16(ka3, qf01, s01);
            f32x4 s10 = {0,0,0,0}, s11 = {0,0,0,0};
            s10 = MFMA16(ka0, qf10, s10);
            s10 = MFMA16(ka1, qf11, s10);
            s11 = MFMA16(ka2, qf10, s11);
            s11 = MFMA16(ka3, qf11, s11);
            __builtin_amdgcn_s_setprio(0);

            bf16v8 pa0 = softmax_exch(s00, s01, rsum0, srcA, srcB, hq);
            bf16v8 pa1 = softmax_exch(s10, s11, rsum1, srcA, srcB, hq);

            __builtin_amdgcn_s_setprio(1);
            o00 = MFMA16(pa0, v0, o00);
            o01 = MFMA16(pa0, v1, o01);
            o02 = MFMA16(pa0, v2, o02);
            o03 = MFMA16(pa0, v3, o03);
            o10 = MFMA16(pa1, v0, o10);
            o11 = MFMA16(pa1, v1, o11);
            o12 = MFMA16(pa1, v2, o12);
            o13 = MFMA16(pa1, v3, o13);
            __builtin_amdgcn_s_setprio(0);
        }

        __syncthreads();   // drains staging vmcnt; flips buffers safely
        cur ^= 1;
    }

    rsum0 += __shfl_xor(rsum0, 16);
    rsum0 += __shfl_xor(rsum0, 32);
    rsum1 += __shfl_xor(rsum1, 16);
    rsum1 += __shfl_xor(rsum1, 32);
    float inv0 = 1.f / rsum0, inv1 = 1.f / rsum1;

    int qrow0 = q0 + hi * 4;
    #pragma unroll
    for (int r = 0; r < 4; ++r) {
        float iq = __shfl(inv0, hi * 4 + r);
        float* op = out + ((size_t)b * NC + qrow0 + r) * NE + lr;
        op[0]  = o00[r] * iq;
        op[16] = o01[r] * iq;
        op[32] = o02[r] * iq;
        op[48] = o03[r] * iq;
    }
    int qrow1 = q0 + 16 + hi * 4;
    #pragma unroll
    for (int r = 0; r < 4; ++r) {
        float iq = __shfl(inv1, hi * 4 + r);
        float* op = out + ((size_t)b * NC + qrow1 + r) * NE + lr;
        op[0]  = o10[r] * iq;
        op[16] = o11[r] * iq;
        op[32] = o12[r] * iq;
        op[48] = o13[r] * iq;
    }
}

// ---------------------------------------------------------------------------
extern "C" void kernel_launch(void* const* d_in, const int* in_sizes, int n_in,
                              void* d_out, int out_size, void* d_ws, size_t ws_size,
                              hipStream_t stream) {
    (void)in_sizes; (void)n_in; (void)out_size; (void)ws_size;
    const float* x      = (const float*)d_in[0];
    const float* conv_w = (const float*)d_in[1];
    const float* conv_b = (const float*)d_in[2];
    const float* ln_g   = (const float*)d_in[3];
    const float* ln_b   = (const float*)d_in[4];
    const float* fi_w   = (const float*)d_in[5];
    const float* fi_b   = (const float*)d_in[6];
    // bi_w/bi_b unused: mask is constant along softmax axis -> exact no-op.

    bf16* qbuf = (bf16*)d_ws;
    bf16* kbuf = qbuf + (size_t)NB * NC * NE;
    bf16* vt2  = kbuf + (size_t)NB * NC * NE;             // tiled V
    float* stats = (float*)(vt2 + (size_t)NB * NC * NE);  // NB*16*64 f32
    float* out = (float*)d_out;

    k_conv<<<dim3(NB * 16), 256, 0, stream>>>(x, conv_w, conv_b, ln_g, ln_b,
                                              qbuf, stats);
    k_vk<<<dim3(12, NB), 256, 0, stream>>>(x, fi_w, fi_b, stats, kbuf, vt2);
    k_attn<<<dim3(768), 256, 0, stream>>>(qbuf, kbuf, vt2, out);
}